// Round 8
// baseline (153.502 us; speedup 1.0000x reference)
//
#include <hip/hip_runtime.h>
#include <math.h>

// CARAFE upsample: B=8, C=128, H=W=64, S=2, K=5, M=64, n_enc=100 (pad 128)
// NOTE: ~60us of dur_us is harness re-poison fill (256MiB ws @ ~46us + 64MiB
// out) inside the timed window — fixed floor we cannot touch.
// 3 dispatches:
//  K0 prep: zero-fill xpad (border zeros), ew->a_prep bf16, cw->cwT
//  K1 compress: x -> m_t bf16 AND xpad interior bf16 (x read once, in regs)
//  K2 main (512 thr): bf16 MFMA encoder conv + pixelshuffle + softmax -> LDS
//               -> fused reassembly -> out. 16 waves/CU for latency hiding.

typedef __attribute__((ext_vector_type(8))) short short8;
typedef __attribute__((ext_vector_type(4))) float floatx4;
typedef __attribute__((ext_vector_type(2))) float v2f;

__device__ __forceinline__ unsigned short f2bf(float f) {
  union { float f; unsigned int u; } v; v.f = f;
  unsigned int u = v.u + 0x7fffu + ((v.u >> 16) & 1u);  // RNE
  return (unsigned short)(u >> 16);
}
__device__ __forceinline__ void unpack2(unsigned int u, float& lo, float& hi) {
  union { unsigned int u; float f; } a, b;
  a.u = u << 16; b.u = u & 0xffff0000u;
  lo = a.f; hi = b.f;
}
__device__ __forceinline__ v2f unpack2v(unsigned int u) {
  union { unsigned int u; float f; } a, b;
  a.u = u << 16; b.u = u & 0xffff0000u;
  return (v2f){a.f, b.f};
}

// ---------------------------------------------------------------------------
// K0: blocks [0,2448): zero-fill xpad (10,027,008 B as 626,688 uint4 chunks).
//     blocks [2448,2768): a_prep[tap][n][mo] = bf16(ew[n][mo][tap]) (n>=100->0)
//                         cwT[c][mo] = cw[mo][c]
// ---------------------------------------------------------------------------
__global__ __launch_bounds__(256) void k_prep_pad(
    const float* __restrict__ ew, const float* __restrict__ cw,
    unsigned short* __restrict__ a_prep, float* __restrict__ cwT,
    unsigned short* __restrict__ xpad) {
  const int blk = blockIdx.x;
  if (blk < 2448) {
    int idx = blk * 256 + (int)threadIdx.x;  // [0, 626688)
    *(uint4*)&xpad[(size_t)idx * 8] = make_uint4(0u, 0u, 0u, 0u);
  } else {
    int idx = (blk - 2448) * 256 + (int)threadIdx.x;  // [0, 81920)
    if (idx < 9 * 128 * 64) {
      int mo = idx & 63;
      int n = (idx >> 6) & 127;
      int tap = idx >> 13;
      float v = (n < 100) ? ew[(n * 64 + mo) * 9 + tap] : 0.f;
      a_prep[idx] = f2bf(v);
    } else {
      int r = idx - 9 * 128 * 64;  // [0, 8192)
      int c = r >> 6, mo = r & 63;
      cwT[c * 64 + mo] = cw[mo * 128 + c];
    }
  }
}

// ---------------------------------------------------------------------------
// K1: m_t[b][h][w][mo] = bf16( sum_c x[b][c][h][w]*cw[mo][c] + cb[mo] )
//     + xpad[b][c][h+2][w+2] = bf16(x[b][c][h][w])  (interior; border zeroed
//       by K0) — x is read exactly once on-chip.
// Block (b,h): 512 x 256. lane = w, wave wv owns mo [16wv,16wv+16) via
// wave-uniform scalar weight loads; wave wv stores xpad for c in [32wv,32wv+32).
// ---------------------------------------------------------------------------
__global__ __launch_bounds__(256) void k_compress(
    const float* __restrict__ x, const float* __restrict__ cwT,
    const float* __restrict__ cb, unsigned short* __restrict__ m_t,
    unsigned short* __restrict__ xpad) {
  __shared__ __align__(16) unsigned short ms[64][72];  // 9.2KB
  const int b = blockIdx.x >> 6;
  const int h = blockIdx.x & 63;
  const int wv = __builtin_amdgcn_readfirstlane((int)(threadIdx.x >> 6));
  const int lane = (int)(threadIdx.x & 63);
  const int mo0 = wv * 16;

  float acc[16];
#pragma unroll
  for (int k = 0; k < 16; ++k) acc[k] = 0.f;

  const float* xp = x + (((size_t)b * 128) * 64 + h) * 64 + lane;
  const float* wp = cwT + mo0;  // wave-uniform
  unsigned short* xpd =
      xpad + ((size_t)(b * 128) * 4896) + (h + 2) * 72 + 2 + lane;

#pragma unroll 4
  for (int c = 0; c < 128; ++c) {
    float xv = xp[(size_t)c * 4096];
    if ((c >> 5) == wv)  // wave-uniform: this wave stores these 32 channels
      xpd[(size_t)c * 4896] = f2bf(xv);
#pragma unroll
    for (int k = 0; k < 16; ++k)
      acc[k] = fmaf(xv, wp[c * 64 + k], acc[k]);
  }

#pragma unroll
  for (int k = 0; k < 16; ++k) acc[k] += cb[mo0 + k];

#pragma unroll
  for (int k = 0; k < 8; ++k) {
    unsigned int p = ((unsigned int)f2bf(acc[2 * k + 1]) << 16) | f2bf(acc[2 * k]);
    *(unsigned int*)&ms[lane][mo0 + 2 * k] = p;
  }
  __syncthreads();
  const int t = threadIdx.x;
#pragma unroll
  for (int rep = 0; rep < 2; ++rep) {
    int idx = t + rep * 256;  // 0..511 -> w = idx>>3 in [0,64)
    uint4 v = *(const uint4*)&ms[idx >> 3][(idx & 7) * 8];
    *(uint4*)&m_t[(size_t)blockIdx.x * 4096 + idx * 8] = v;
  }
}

// ---------------------------------------------------------------------------
// K2 main (fused encoder+softmax+reassemble). Block per (b,h): 512 x 512 thr
// (8 waves; 2 blocks/CU -> 16 waves/CU for latency hiding).
// Phase A: wave wv owns n [16wv,16wv+16): 1 n-tile x 4 px-tiles, 72 MFMA.
// Softmax: waves 0-3 (q=wave, px=lane).
// Phase B: thread = (wg 16 x cg 32): 4ch x 4w x 2ow x 2oh, no chalf loop.
// LDS union: m_s (27.6KB) / raw (33.8KB) / wgt_s (12.8KB).
// ---------------------------------------------------------------------------
__global__ __launch_bounds__(512, 4) void k_main(
    const unsigned short* __restrict__ m_t, const unsigned short* __restrict__ a_prep,
    const float* __restrict__ eb, const unsigned short* __restrict__ xpad,
    float* __restrict__ out) {
  __shared__ __align__(16) float raw[128 * 66];   // 33.8KB union
  unsigned short* m_s = (unsigned short*)raw;     // [dh][w][mo pad72] 27.6KB
  unsigned short* wgt_s = (unsigned short*)raw;   // [oh2][kk25][ow128] 12.8KB
  const int b = blockIdx.x >> 6;
  const int h = blockIdx.x & 63;
  const int t = threadIdx.x;

  // ---- Phase A: stage m rows h-1,h,h+1 ----
  for (int idx = t; idx < 3 * 64 * 8; idx += 512) {
    int r = idx >> 9;
    int rem = idx & 511;
    int w = rem >> 3, u = rem & 7;
    int hh = h + r - 1;
    uint4 val = make_uint4(0u, 0u, 0u, 0u);
    if (hh >= 0 && hh < 64)
      val = *(const uint4*)&m_t[(((b * 64 + hh) * 64 + w) * 64) + u * 8];
    *(uint4*)&m_s[(r * 64 + w) * 72 + u * 8] = val;
  }
  __syncthreads();

  const int wave = t >> 6, lane = t & 63;
  const int quad = lane >> 4, col = lane & 15;
  const int nbase = wave * 16;  // 8 waves x 16 n = 128

  const floatx4 z4 = {0.f, 0.f, 0.f, 0.f};
  floatx4 acc[4];
#pragma unroll
  for (int p = 0; p < 4; ++p) acc[p] = z4;

  const short8 z8 = {0, 0, 0, 0, 0, 0, 0, 0};

#pragma unroll
  for (int tap = 0; tap < 9; ++tap) {
    const int dh = tap / 3, dw = tap % 3;
#pragma unroll
    for (int half = 0; half < 2; ++half) {
      const int mo0 = half * 32;
      short8 a0 = *(const short8*)&a_prep[((tap * 128 + nbase + col) * 64) + mo0 + quad * 8];
#pragma unroll
      for (int p = 0; p < 4; ++p) {
        int wsrc = p * 16 + col + dw - 1;
        int wc = min(max(wsrc, 0), 63);
        short8 bf = *(const short8*)&m_s[(dh * 64 + wc) * 72 + mo0 + quad * 8];
        if (wsrc < 0 || wsrc > 63) bf = z8;
        acc[p] = __builtin_amdgcn_mfma_f32_16x16x32_bf16(a0, bf, acc[p], 0, 0, 0);
      }
    }
  }

  __syncthreads();  // m_s dead; raw takes over the union
#pragma unroll
  for (int p = 0; p < 4; ++p)
#pragma unroll
    for (int r = 0; r < 4; ++r)
      raw[(nbase + quad * 4 + r) * 66 + p * 16 + col] = acc[p][r];
  __syncthreads();

  // softmax over kk (n = kk*4+q): waves 0-3, q = wave, px = lane
  float v[25];
  float inv = 0.f;
  if (t < 256) {
    const int q = wave;
    float mx = -1e30f;
#pragma unroll
    for (int kk = 0; kk < 25; ++kk) {
      v[kk] = raw[(kk * 4 + q) * 66 + lane] + eb[kk * 4 + q];
      mx = fmaxf(mx, v[kk]);
    }
    float s = 0.f;
#pragma unroll
    for (int kk = 0; kk < 25; ++kk) {
      v[kk] = __expf(v[kk] - mx);
      s += v[kk];
    }
    inv = 1.f / s;
  }
  __syncthreads();  // raw reads done; wgt_s takes over the union
  if (t < 256) {
    const int q = wave;
    const int ohl = q >> 1;
    const int owp = 2 * lane + (q & 1);
#pragma unroll
    for (int kk = 0; kk < 25; ++kk)
      wgt_s[(ohl * 25 + kk) * 128 + owp] = f2bf(v[kk] * inv);
  }
  __syncthreads();

  // ---- Phase B: reassembly ----
  const int wg = t & 15;
  const int cg = t >> 4;  // [0,32)
  const int w0 = wg * 4;
  const int c0 = cg * 4;

  const unsigned short* xb =
      xpad + ((size_t)(b * 128 + c0) * 4896) + h * 72 + w0;

  v2f accB[2][4][4];  // [oh][ch][k]
#pragma unroll
  for (int oh = 0; oh < 2; ++oh)
#pragma unroll
    for (int ch = 0; ch < 4; ++ch)
#pragma unroll
      for (int k = 0; k < 4; ++k) accB[oh][ch][k] = (v2f){0.f, 0.f};

  for (int i = 0; i < 5; ++i) {
    float xr[4][8];
#pragma unroll
    for (int ch = 0; ch < 4; ++ch) {
      uint4 rawv = *(const uint4*)(xb + ch * 4896 + i * 72);
      unpack2(rawv.x, xr[ch][0], xr[ch][1]);
      unpack2(rawv.y, xr[ch][2], xr[ch][3]);
      unpack2(rawv.z, xr[ch][4], xr[ch][5]);
      unpack2(rawv.w, xr[ch][6], xr[ch][7]);
    }
#pragma unroll
    for (int j = 0; j < 5; ++j) {
      const int ij = i * 5 + j;
#pragma unroll
      for (int oh = 0; oh < 2; ++oh) {
        uint4 wr = *(const uint4*)&wgt_s[(oh * 25 + ij) * 128 + w0 * 2];
        v2f wp[4];
        wp[0] = unpack2v(wr.x);
        wp[1] = unpack2v(wr.y);
        wp[2] = unpack2v(wr.z);
        wp[3] = unpack2v(wr.w);
#pragma unroll
        for (int k = 0; k < 4; ++k)
#pragma unroll
          for (int ch = 0; ch < 4; ++ch) {
            float xv = xr[ch][k + j];
            v2f xvv = {xv, xv};
            accB[oh][ch][k] += xvv * wp[k];  // v_pk_fma_f32
          }
      }
    }
  }

#pragma unroll
  for (int ch = 0; ch < 4; ++ch)
#pragma unroll
    for (int oh = 0; oh < 2; ++oh) {
      float* orow =
          out + ((size_t)(b * 128 + c0 + ch) * 128 + (2 * h + oh)) * 128 + w0 * 2;
      float4 f0 = make_float4(accB[oh][ch][0].x, accB[oh][ch][0].y,
                              accB[oh][ch][1].x, accB[oh][ch][1].y);
      float4 f1 = make_float4(accB[oh][ch][2].x, accB[oh][ch][2].y,
                              accB[oh][ch][3].x, accB[oh][ch][3].y);
      *(float4*)orow = f0;
      *(float4*)(orow + 4) = f1;
    }
}

// ---------------------------------------------------------------------------
extern "C" void kernel_launch(void* const* d_in, const int* in_sizes, int n_in,
                              void* d_out, int out_size, void* d_ws, size_t ws_size,
                              hipStream_t stream) {
  (void)in_sizes; (void)n_in; (void)out_size; (void)ws_size;
  const float* x  = (const float*)d_in[0];
  const float* cw = (const float*)d_in[1];
  const float* cb = (const float*)d_in[2];
  const float* ew = (const float*)d_in[3];
  const float* eb = (const float*)d_in[4];
  float* out = (float*)d_out;

  char* wsb = (char*)d_ws;
  unsigned short* m_t    = (unsigned short*)(wsb);               // 4,194,304 B
  unsigned short* a_prep = (unsigned short*)(wsb + 4194304);     //   147,456 B
  unsigned short* xpad   = (unsigned short*)(wsb + 4341760);     // 10,027,008 B
  float*          cwT    = (float*)(wsb + 14368768);             //    32,768 B

  k_prep_pad<<<dim3(2768), dim3(256), 0, stream>>>(ew, cw, a_prep, cwT, xpad);
  k_compress<<<dim3(512), dim3(256), 0, stream>>>(x, cwT, cb, m_t, xpad);
  k_main<<<dim3(512), dim3(512), 0, stream>>>(m_t, a_prep, eb, xpad, out);
}

// Round 9
// 145.687 us; speedup vs baseline: 1.0536x; 1.0536x over previous
//
#include <hip/hip_runtime.h>
#include <math.h>

// CARAFE upsample: B=8, C=128, H=W=64, S=2, K=5, M=64, n_enc=100 (pad 128)
// NOTE: ~60us of dur_us is harness re-poison fill (256MiB ws @ ~46us + 64MiB
// out) inside the timed window — fixed floor we cannot touch.
// 3 dispatches:
//  K0 prep: zero-fill xpad, ew->a_prep bf16, cw->cwT
//  K1 compress: x -> m_t bf16 AND xpad interior bf16 (x read once)
//  K2 main (256 thr, R7 structure): bf16 MFMA encoder conv + pixelshuffle +
//     softmax -> LDS wgt -> fused reassembly -> out.
// XCD swizzle (R9): blk&7 selects an h-stripe of 8, identically in K1 and K2,
// so producer/consumer rows stay in one XCD's L2 (m09: 8 XCDs round-robin).

typedef __attribute__((ext_vector_type(8))) short short8;
typedef __attribute__((ext_vector_type(4))) float floatx4;
typedef __attribute__((ext_vector_type(2))) float v2f;

__device__ __forceinline__ unsigned short f2bf(float f) {
  union { float f; unsigned int u; } v; v.f = f;
  unsigned int u = v.u + 0x7fffu + ((v.u >> 16) & 1u);  // RNE
  return (unsigned short)(u >> 16);
}
__device__ __forceinline__ void unpack2(unsigned int u, float& lo, float& hi) {
  union { unsigned int u; float f; } a, b;
  a.u = u << 16; b.u = u & 0xffff0000u;
  lo = a.f; hi = b.f;
}
__device__ __forceinline__ v2f unpack2v(unsigned int u) {
  union { unsigned int u; float f; } a, b;
  a.u = u << 16; b.u = u & 0xffff0000u;
  return (v2f){a.f, b.f};
}
// blk in [0,512) -> (b,h) with h-stripe = blk&7 (XCD slot)
__device__ __forceinline__ void swizzle_bh(int blk, int& b, int& h) {
  int x = blk & 7;
  int i = blk >> 3;   // [0,64)
  b = i >> 3;         // [0,8)
  h = x * 8 + (i & 7);
}

// ---------------------------------------------------------------------------
// K0: blocks [0,2448): zero-fill xpad (10,027,008 B as uint4 chunks).
//     blocks [2448,2768): a_prep[tap][n][mo] = bf16(ew[n][mo][tap]) (n>=100->0)
//                         cwT[c][mo] = cw[mo][c]
// ---------------------------------------------------------------------------
__global__ __launch_bounds__(256) void k_prep_pad(
    const float* __restrict__ ew, const float* __restrict__ cw,
    unsigned short* __restrict__ a_prep, float* __restrict__ cwT,
    unsigned short* __restrict__ xpad) {
  const int blk = blockIdx.x;
  if (blk < 2448) {
    int idx = blk * 256 + (int)threadIdx.x;  // [0, 626688)
    *(uint4*)&xpad[(size_t)idx * 8] = make_uint4(0u, 0u, 0u, 0u);
  } else {
    int idx = (blk - 2448) * 256 + (int)threadIdx.x;  // [0, 81920)
    if (idx < 9 * 128 * 64) {
      int mo = idx & 63;
      int n = (idx >> 6) & 127;
      int tap = idx >> 13;
      float v = (n < 100) ? ew[(n * 64 + mo) * 9 + tap] : 0.f;
      a_prep[idx] = f2bf(v);
    } else {
      int r = idx - 9 * 128 * 64;  // [0, 8192)
      int c = r >> 6, mo = r & 63;
      cwT[c * 64 + mo] = cw[mo * 128 + c];
    }
  }
}

// ---------------------------------------------------------------------------
// K1: m_t[b][h][w][mo] = bf16( sum_c x[b][c][h][w]*cw[mo][c] + cb[mo] )
//     + xpad[b][c][h+2][w+2] = bf16(x[b][c][h][w])  (border zeroed by K0).
// Block (swizzled b,h): 512 x 256. lane = w; wave wv owns mo [16wv,16wv+16)
// via wave-uniform scalar weight loads; wave wv stores xpad c in [32wv,+32).
// ---------------------------------------------------------------------------
__global__ __launch_bounds__(256) void k_compress(
    const float* __restrict__ x, const float* __restrict__ cwT,
    const float* __restrict__ cb, unsigned short* __restrict__ m_t,
    unsigned short* __restrict__ xpad) {
  __shared__ __align__(16) unsigned short ms[64][72];  // 9.2KB
  int b, h;
  swizzle_bh(blockIdx.x, b, h);
  const int wv = __builtin_amdgcn_readfirstlane((int)(threadIdx.x >> 6));
  const int lane = (int)(threadIdx.x & 63);
  const int mo0 = wv * 16;

  float acc[16];
#pragma unroll
  for (int k = 0; k < 16; ++k) acc[k] = 0.f;

  const float* xp = x + (((size_t)b * 128) * 64 + h) * 64 + lane;
  const float* wp = cwT + mo0;  // wave-uniform
  unsigned short* xpd =
      xpad + ((size_t)(b * 128) * 4896) + (h + 2) * 72 + 2 + lane;

#pragma unroll 4
  for (int c = 0; c < 128; ++c) {
    float xv = xp[(size_t)c * 4096];
    if ((c >> 5) == wv)  // wave-uniform branch
      xpd[(size_t)c * 4896] = f2bf(xv);
#pragma unroll
    for (int k = 0; k < 16; ++k)
      acc[k] = fmaf(xv, wp[c * 64 + k], acc[k]);
  }

#pragma unroll
  for (int k = 0; k < 16; ++k) acc[k] += cb[mo0 + k];

#pragma unroll
  for (int k = 0; k < 8; ++k) {
    unsigned int p = ((unsigned int)f2bf(acc[2 * k + 1]) << 16) | f2bf(acc[2 * k]);
    *(unsigned int*)&ms[lane][mo0 + 2 * k] = p;
  }
  __syncthreads();
  const int t = threadIdx.x;
  const size_t mbase = (size_t)(b * 64 + h) * 4096;
#pragma unroll
  for (int rep = 0; rep < 2; ++rep) {
    int idx = t + rep * 256;  // 0..511 -> w = idx>>3 in [0,64)
    uint4 v = *(const uint4*)&ms[idx >> 3][(idx & 7) * 8];
    *(uint4*)&m_t[mbase + idx * 8] = v;
  }
}

// ---------------------------------------------------------------------------
// K2 main (fused encoder+softmax+reassemble). Block per swizzled (b,h):
// 512 x 256 (R7 structure — 4 waves, chalf loop, no VGPR cap).
// Phase A: wave owns n [32w,32w+32): 2 n-tiles x 4 px-tiles, 8 MFMA/k-step.
// Phase B: thread = (wg 16 x cg 16), 4ch x 4w x 2ow x 2oh regs, chalf loop.
// LDS union: m_s (27.6KB) / raw (33.8KB) / wgt_s (12.8KB).
// ---------------------------------------------------------------------------
__global__ __launch_bounds__(256) void k_main(
    const unsigned short* __restrict__ m_t, const unsigned short* __restrict__ a_prep,
    const float* __restrict__ eb, const unsigned short* __restrict__ xpad,
    float* __restrict__ out) {
  __shared__ __align__(16) float raw[128 * 66];   // 33.8KB union
  unsigned short* m_s = (unsigned short*)raw;     // [dh][w][mo pad72] 27.6KB
  unsigned short* wgt_s = (unsigned short*)raw;   // [oh2][kk25][ow128] 12.8KB
  int b, h;
  swizzle_bh(blockIdx.x, b, h);
  const int t = threadIdx.x;

  // ---- Phase A: stage m rows h-1,h,h+1 ----
  for (int idx = t; idx < 3 * 64 * 8; idx += 256) {
    int r = idx >> 9;
    int rem = idx & 511;
    int w = rem >> 3, u = rem & 7;
    int hh = h + r - 1;
    uint4 val = make_uint4(0u, 0u, 0u, 0u);
    if (hh >= 0 && hh < 64)
      val = *(const uint4*)&m_t[(((size_t)(b * 64 + hh) * 64 + w) * 64) + u * 8];
    *(uint4*)&m_s[(r * 64 + w) * 72 + u * 8] = val;
  }
  __syncthreads();

  const int wave = t >> 6, lane = t & 63;
  const int quad = lane >> 4, col = lane & 15;
  const int nbase = wave * 32;

  const floatx4 z4 = {0.f, 0.f, 0.f, 0.f};
  floatx4 acc[2][4];
#pragma unroll
  for (int i = 0; i < 2; ++i)
#pragma unroll
    for (int p = 0; p < 4; ++p) acc[i][p] = z4;

  const short8 z8 = {0, 0, 0, 0, 0, 0, 0, 0};

#pragma unroll
  for (int tap = 0; tap < 9; ++tap) {
    const int dh = tap / 3, dw = tap % 3;
#pragma unroll
    for (int half = 0; half < 2; ++half) {
      const int mo0 = half * 32;
      short8 a0 = *(const short8*)&a_prep[((tap * 128 + nbase + col) * 64) + mo0 + quad * 8];
      short8 a1 = *(const short8*)&a_prep[((tap * 128 + nbase + 16 + col) * 64) + mo0 + quad * 8];
#pragma unroll
      for (int p = 0; p < 4; ++p) {
        int wsrc = p * 16 + col + dw - 1;
        int wc = min(max(wsrc, 0), 63);
        short8 bf = *(const short8*)&m_s[(dh * 64 + wc) * 72 + mo0 + quad * 8];
        if (wsrc < 0 || wsrc > 63) bf = z8;
        acc[0][p] = __builtin_amdgcn_mfma_f32_16x16x32_bf16(a0, bf, acc[0][p], 0, 0, 0);
        acc[1][p] = __builtin_amdgcn_mfma_f32_16x16x32_bf16(a1, bf, acc[1][p], 0, 0, 0);
      }
    }
  }

  __syncthreads();  // m_s dead; raw takes over the union
#pragma unroll
  for (int i = 0; i < 2; ++i)
#pragma unroll
    for (int p = 0; p < 4; ++p)
#pragma unroll
      for (int r = 0; r < 4; ++r)
        raw[(nbase + i * 16 + quad * 4 + r) * 66 + p * 16 + col] = acc[i][p][r];
  __syncthreads();

  // softmax over kk (n = kk*4+q), q = wave, px = lane
  const int q = wave;
  float v[25];
  float mx = -1e30f;
#pragma unroll
  for (int kk = 0; kk < 25; ++kk) {
    v[kk] = raw[(kk * 4 + q) * 66 + lane] + eb[kk * 4 + q];
    mx = fmaxf(mx, v[kk]);
  }
  float s = 0.f;
#pragma unroll
  for (int kk = 0; kk < 25; ++kk) {
    v[kk] = __expf(v[kk] - mx);
    s += v[kk];
  }
  float inv = 1.f / s;

  __syncthreads();  // raw reads done; wgt_s takes over the union
  {
    const int ohl = q >> 1;
    const int owp = 2 * lane + (q & 1);
#pragma unroll
    for (int kk = 0; kk < 25; ++kk)
      wgt_s[(ohl * 25 + kk) * 128 + owp] = f2bf(v[kk] * inv);
  }
  __syncthreads();

  // ---- Phase B: reassembly, both channel halves ----
  const int wg = t & 15;
  const int cg = t >> 4;
  const int w0 = wg * 4;

  for (int chalf = 0; chalf < 2; ++chalf) {
    const int c0 = chalf * 64 + cg * 4;
    const unsigned short* xb =
        xpad + ((size_t)(b * 128 + c0) * 4896) + h * 72 + w0;

    v2f accB[2][4][4];  // [oh][ch][k]
#pragma unroll
    for (int oh = 0; oh < 2; ++oh)
#pragma unroll
      for (int ch = 0; ch < 4; ++ch)
#pragma unroll
        for (int k = 0; k < 4; ++k) accB[oh][ch][k] = (v2f){0.f, 0.f};

    for (int i = 0; i < 5; ++i) {
      float xr[4][8];
#pragma unroll
      for (int ch = 0; ch < 4; ++ch) {
        uint4 rawv = *(const uint4*)(xb + ch * 4896 + i * 72);
        unpack2(rawv.x, xr[ch][0], xr[ch][1]);
        unpack2(rawv.y, xr[ch][2], xr[ch][3]);
        unpack2(rawv.z, xr[ch][4], xr[ch][5]);
        unpack2(rawv.w, xr[ch][6], xr[ch][7]);
      }
#pragma unroll
      for (int j = 0; j < 5; ++j) {
        const int ij = i * 5 + j;
#pragma unroll
        for (int oh = 0; oh < 2; ++oh) {
          uint4 wr = *(const uint4*)&wgt_s[(oh * 25 + ij) * 128 + w0 * 2];
          v2f wp[4];
          wp[0] = unpack2v(wr.x);
          wp[1] = unpack2v(wr.y);
          wp[2] = unpack2v(wr.z);
          wp[3] = unpack2v(wr.w);
#pragma unroll
          for (int k = 0; k < 4; ++k)
#pragma unroll
            for (int ch = 0; ch < 4; ++ch) {
              float xv = xr[ch][k + j];
              v2f xvv = {xv, xv};
              accB[oh][ch][k] += xvv * wp[k];  // v_pk_fma_f32
            }
        }
      }
    }

#pragma unroll
    for (int ch = 0; ch < 4; ++ch)
#pragma unroll
      for (int oh = 0; oh < 2; ++oh) {
        float* orow =
            out + ((size_t)(b * 128 + c0 + ch) * 128 + (2 * h + oh)) * 128 + w0 * 2;
        float4 f0 = make_float4(accB[oh][ch][0].x, accB[oh][ch][0].y,
                                accB[oh][ch][1].x, accB[oh][ch][1].y);
        float4 f1 = make_float4(accB[oh][ch][2].x, accB[oh][ch][2].y,
                                accB[oh][ch][3].x, accB[oh][ch][3].y);
        *(float4*)orow = f0;
        *(float4*)(orow + 4) = f1;
      }
  }
}

// ---------------------------------------------------------------------------
extern "C" void kernel_launch(void* const* d_in, const int* in_sizes, int n_in,
                              void* d_out, int out_size, void* d_ws, size_t ws_size,
                              hipStream_t stream) {
  (void)in_sizes; (void)n_in; (void)out_size; (void)ws_size;
  const float* x  = (const float*)d_in[0];
  const float* cw = (const float*)d_in[1];
  const float* cb = (const float*)d_in[2];
  const float* ew = (const float*)d_in[3];
  const float* eb = (const float*)d_in[4];
  float* out = (float*)d_out;

  char* wsb = (char*)d_ws;
  unsigned short* m_t    = (unsigned short*)(wsb);               // 4,194,304 B
  unsigned short* a_prep = (unsigned short*)(wsb + 4194304);     //   147,456 B
  unsigned short* xpad   = (unsigned short*)(wsb + 4341760);     // 10,027,008 B
  float*          cwT    = (float*)(wsb + 14368768);             //    32,768 B

  k_prep_pad<<<dim3(2768), dim3(256), 0, stream>>>(ew, cw, a_prep, cwT, xpad);
  k_compress<<<dim3(512), dim3(256), 0, stream>>>(x, cwT, cb, m_t, xpad);
  k_main<<<dim3(512), dim3(256), 0, stream>>>(m_t, a_prep, eb, xpad, out);
}